// Round 1
// baseline (777.235 us; speedup 1.0000x reference)
//
#include <hip/hip_runtime.h>
#include <math.h>

#define Bc 4
#define Nc 256
#define Tc 128
#define Dc 512
#define Hc 8
#define HDc 64

__device__ __forceinline__ float4 f4add(float4 a, float4 b) {
    return make_float4(a.x + b.x, a.y + b.y, a.z + b.z, a.w + b.w);
}

// ---------------- Kernel 1: x_repr = mean over T -------------------------
// grid: B*N blocks, 128 threads (one float4 column each)
__global__ __launch_bounds__(128) void mean_kernel(const float* __restrict__ x,
                                                   float* __restrict__ xr) {
    const int bn = blockIdx.x;
    const int col = threadIdx.x;  // 0..127
    const float4* xp = (const float4*)x + (size_t)bn * (Tc * Dc / 4) + col;
    float4 a0 = make_float4(0.f, 0.f, 0.f, 0.f), a1 = a0, a2 = a0, a3 = a0;
    for (int t = 0; t < Tc; t += 4) {
        a0 = f4add(a0, xp[(size_t)(t + 0) * (Dc / 4)]);
        a1 = f4add(a1, xp[(size_t)(t + 1) * (Dc / 4)]);
        a2 = f4add(a2, xp[(size_t)(t + 2) * (Dc / 4)]);
        a3 = f4add(a3, xp[(size_t)(t + 3) * (Dc / 4)]);
    }
    float4 s = f4add(f4add(a0, a1), f4add(a2, a3));
    const float r = 1.0f / Tc;
    ((float4*)xr)[(size_t)bn * (Dc / 4) + col] =
        make_float4(s.x * r, s.y * r, s.z * r, s.w * r);
}

// ---------------- Generic NT GEMM tile: Y = A @ W^T + bias ---------------
// A: 1024 x 512 row-major, W: 512 x 512 row-major, Y row stride 512.
// block = 256 threads, computes 64x64 tile, 4x4 per thread.
__device__ __forceinline__ void gemm_tile(const float* __restrict__ A,
                                          const float* __restrict__ W,
                                          const float* __restrict__ bias,
                                          float* __restrict__ Y, int it, int jt) {
    __shared__ float As[64][65];  // [k][i], +1 pad: conflict-free transposed writes
    __shared__ float Ws[64][65];  // [k][j]
    const int tid = threadIdx.x;
    const int ty = tid >> 4, tx = tid & 15;
    const int i0 = it * 64, j0 = jt * 64;
    float acc[4][4] = {{0.f}};
    for (int kb = 0; kb < 8; ++kb) {
        const int k0 = kb * 64;
#pragma unroll
        for (int p = 0; p < 16; ++p) {
            int idx = p * 256 + tid;
            int r = idx >> 6, c = idx & 63;  // coalesced over c (k)
            As[c][r] = A[(size_t)(i0 + r) * Dc + k0 + c];
            Ws[c][r] = W[(size_t)(j0 + r) * Dc + k0 + c];
        }
        __syncthreads();
#pragma unroll 16
        for (int kk = 0; kk < 64; ++kk) {
            float a0 = As[kk][ty * 4 + 0], a1 = As[kk][ty * 4 + 1];
            float a2 = As[kk][ty * 4 + 2], a3 = As[kk][ty * 4 + 3];
            float w0 = Ws[kk][tx * 4 + 0], w1 = Ws[kk][tx * 4 + 1];
            float w2 = Ws[kk][tx * 4 + 2], w3 = Ws[kk][tx * 4 + 3];
            acc[0][0] += a0 * w0; acc[0][1] += a0 * w1; acc[0][2] += a0 * w2; acc[0][3] += a0 * w3;
            acc[1][0] += a1 * w0; acc[1][1] += a1 * w1; acc[1][2] += a1 * w2; acc[1][3] += a1 * w3;
            acc[2][0] += a2 * w0; acc[2][1] += a2 * w1; acc[2][2] += a2 * w2; acc[2][3] += a2 * w3;
            acc[3][0] += a3 * w0; acc[3][1] += a3 * w1; acc[3][2] += a3 * w2; acc[3][3] += a3 * w3;
        }
        __syncthreads();
    }
#pragma unroll
    for (int r = 0; r < 4; ++r) {
        int i = i0 + ty * 4 + r;
        int j = j0 + tx * 4;
        float4 o = make_float4(acc[r][0] + bias[j + 0], acc[r][1] + bias[j + 1],
                               acc[r][2] + bias[j + 2], acc[r][3] + bias[j + 3]);
        *(float4*)&Y[(size_t)i * Dc + j] = o;
    }
}

// Fused QKV: grid (16, 24); blockIdx.y>>3 selects matrix, &7 selects j-tile.
__global__ __launch_bounds__(256) void qkv_kernel(
    const float* __restrict__ xr, const float* __restrict__ Wq, const float* __restrict__ bq,
    const float* __restrict__ Wk, const float* __restrict__ bk,
    const float* __restrict__ Wv, const float* __restrict__ bv,
    float* __restrict__ Yq, float* __restrict__ Yk, float* __restrict__ Yv) {
    const int it = blockIdx.x;
    const int mat = blockIdx.y >> 3;
    const int jt = blockIdx.y & 7;
    const float* W = (mat == 0) ? Wq : (mat == 1) ? Wk : Wv;
    const float* b = (mat == 0) ? bq : (mat == 1) ? bk : bv;
    float* Y = (mat == 0) ? Yq : (mat == 1) ? Yk : Yv;
    gemm_tile(xr, W, b, Y, it, jt);
}

// O projection: grid (16, 8)
__global__ __launch_bounds__(256) void oproj_kernel(const float* __restrict__ attn,
                                                    const float* __restrict__ Wo,
                                                    const float* __restrict__ bo,
                                                    float* __restrict__ Y) {
    gemm_tile(attn, Wo, bo, Y, blockIdx.x, blockIdx.y);
}

// ---------------- Kernel 3: bias[b,h,n,m] (haversine MLP + mask) ---------
// grid: B*N blocks (one per (b,n)), 256 threads (one per m)
__global__ __launch_bounds__(256) void bias_kernel(
    const float* __restrict__ coords, const int* __restrict__ mask,
    const float* __restrict__ Wd1, const float* __restrict__ bd1,
    const float* __restrict__ Wd2, const float* __restrict__ bd2,
    float* __restrict__ biasb) {
    const int b = blockIdx.x >> 8;
    const int n = blockIdx.x & 255;
    const int m = threadIdx.x;
    __shared__ float swd1[64], sbd1[64], swd2[512], sbd2[8];
    if (threadIdx.x < 64) {
        swd1[threadIdx.x] = Wd1[threadIdx.x];
        sbd1[threadIdx.x] = bd1[threadIdx.x];
    }
    if (threadIdx.x < 8) sbd2[threadIdx.x] = bd2[threadIdx.x];
    swd2[threadIdx.x] = Wd2[threadIdx.x];
    swd2[threadIdx.x + 256] = Wd2[threadIdx.x + 256];
    __syncthreads();

    const float DEG = 0.017453292519943295f;  // pi/180
    float lat1 = coords[((size_t)b * Nc + n) * 2 + 0] * DEG;
    float lon1 = coords[((size_t)b * Nc + n) * 2 + 1] * DEG;
    float lat2 = coords[((size_t)b * Nc + m) * 2 + 0] * DEG;
    float lon2 = coords[((size_t)b * Nc + m) * 2 + 1] * DEG;
    float sdlat = sinf((lat2 - lat1) * 0.5f);
    float sdlon = sinf((lon2 - lon1) * 0.5f);
    float a = sdlat * sdlat + cosf(lat1) * cosf(lat2) * sdlon * sdlon;
    a = fminf(fmaxf(a, 0.0f), 1.0f);
    float c = 2.0f * atan2f(sqrtf(a), sqrtf(1.0f - a));
    float dist = 6371.0f * c;

    float acc[8];
#pragma unroll
    for (int h = 0; h < 8; ++h) acc[h] = sbd2[h];
#pragma unroll 8
    for (int k = 0; k < 64; ++k) {
        float hm = fmaxf(dist * swd1[k] + sbd1[k], 0.0f);
#pragma unroll
        for (int h = 0; h < 8; ++h) acc[h] += hm * swd2[h * 64 + k];
    }
    const bool masked = (mask[(size_t)b * Nc + m] == 0);
#pragma unroll
    for (int h = 0; h < 8; ++h) {
        biasb[(((size_t)(b * Hc + h) * Nc + n) * Nc) + m] = masked ? -1e30f : acc[h];
    }
}

// ---------------- Kernel 4: attention --------------------------------------
// grid: B*H*(N/4) = 2048 blocks, 256 threads = 4 waves; wave = one query row.
__global__ __launch_bounds__(256) void attn_kernel(
    const float* __restrict__ Yq, const float* __restrict__ Yk,
    const float* __restrict__ Yv, const float* __restrict__ biasb,
    float* __restrict__ attn) {
    const int bh = blockIdx.x >> 6;   // 0..31
    const int ng = blockIdx.x & 63;   // 0..63
    const int b = bh >> 3, h = bh & 7;
    const int wave = threadIdx.x >> 6;
    const int lane = threadIdx.x & 63;
    const int n = ng * 4 + wave;

    __shared__ float sq[4][64];
    __shared__ float sw[4][256];

    // stage q row (fold 1/sqrt(hd)=1/8 into q)
    sq[wave][lane] = Yq[((size_t)(b * Nc + n)) * Dc + h * HDc + lane] * 0.125f;
    __syncthreads();

    const float4* q4 = (const float4*)sq[wave];
    float s[4];
    float mx = -INFINITY;
#pragma unroll
    for (int rep = 0; rep < 4; ++rep) {
        const int m = rep * 64 + lane;
        const float4* kp = (const float4*)(Yk + ((size_t)(b * Nc + m)) * Dc + h * HDc);
        float acc = 0.f;
#pragma unroll
        for (int kk = 0; kk < 16; ++kk) {
            float4 kv = kp[kk];
            float4 qv = q4[kk];
            acc += kv.x * qv.x + kv.y * qv.y + kv.z * qv.z + kv.w * qv.w;
        }
        float sc = acc + biasb[((size_t)bh * Nc + n) * Nc + m];
        s[rep] = sc;
        mx = fmaxf(mx, sc);
    }
#pragma unroll
    for (int off = 32; off > 0; off >>= 1) mx = fmaxf(mx, __shfl_xor(mx, off, 64));

    float sum = 0.f;
#pragma unroll
    for (int rep = 0; rep < 4; ++rep) {
        float e = expf(s[rep] - mx);
        sw[wave][rep * 64 + lane] = e;
        sum += e;
    }
#pragma unroll
    for (int off = 32; off > 0; off >>= 1) sum += __shfl_xor(sum, off, 64);
    const float inv = 1.0f / sum;
    __syncthreads();

    // out[n, k=lane] = sum_m w_m * V[m][k]
    float o = 0.f;
    const float* vb = Yv + (size_t)b * Nc * Dc + h * HDc + lane;
    const float4* sw4 = (const float4*)sw[wave];
#pragma unroll 8
    for (int mq = 0; mq < 64; ++mq) {
        float4 w4 = sw4[mq];
        const int m = mq * 4;
        o += w4.x * vb[(size_t)(m + 0) * Dc];
        o += w4.y * vb[(size_t)(m + 1) * Dc];
        o += w4.z * vb[(size_t)(m + 2) * Dc];
        o += w4.w * vb[(size_t)(m + 3) * Dc];
    }
    attn[((size_t)(b * Nc + n)) * Dc + h * HDc + lane] = o * inv;
}

// ---------------- Kernel 6: broadcast over T -------------------------------
// grid: B*N blocks, 256 threads
__global__ __launch_bounds__(256) void bcast_kernel(const float* __restrict__ y,
                                                    float* __restrict__ out) {
    const int bn = blockIdx.x;
    __shared__ float4 row[128];
    if (threadIdx.x < 128) row[threadIdx.x] = ((const float4*)y)[(size_t)bn * 128 + threadIdx.x];
    __syncthreads();
    float4* op = (float4*)out + (size_t)bn * (Tc * Dc / 4);
#pragma unroll 4
    for (int it = 0; it < 64; ++it) {
        const int idx = it * 256 + threadIdx.x;  // enumerates t*128 + col
        op[idx] = row[idx & 127];
    }
}

extern "C" void kernel_launch(void* const* d_in, const int* in_sizes, int n_in,
                              void* d_out, int out_size, void* d_ws, size_t ws_size,
                              hipStream_t stream) {
    const float* x      = (const float*)d_in[0];
    const float* coords = (const float*)d_in[1];
    const int*   smask  = (const int*)d_in[2];
    const float* Wq = (const float*)d_in[3];  const float* bq = (const float*)d_in[4];
    const float* Wk = (const float*)d_in[5];  const float* bk = (const float*)d_in[6];
    const float* Wv = (const float*)d_in[7];  const float* bv = (const float*)d_in[8];
    const float* Wo = (const float*)d_in[9];  const float* bo = (const float*)d_in[10];
    const float* Wd1 = (const float*)d_in[11]; const float* bd1 = (const float*)d_in[12];
    const float* Wd2 = (const float*)d_in[13]; const float* bd2 = (const float*)d_in[14];
    float* out = (float*)d_out;

    // workspace layout (floats): all buffers fully rewritten every call
    float* ws    = (float*)d_ws;
    const size_t BND = (size_t)Bc * Nc * Dc;           // 524288
    float* xr    = ws;                                  // x_repr
    float* Yq    = xr + BND;
    float* Yk    = Yq + BND;
    float* Yv    = Yk + BND;
    float* biasb = Yv + BND;                            // B*H*N*N = 2097152
    float* attn  = biasb + (size_t)Bc * Hc * Nc * Nc;
    float* yout  = attn + BND;                          // total ~21 MB

    mean_kernel<<<Bc * Nc, 128, 0, stream>>>(x, xr);
    qkv_kernel<<<dim3(16, 24), 256, 0, stream>>>(xr, Wq, bq, Wk, bk, Wv, bv, Yq, Yk, Yv);
    bias_kernel<<<Bc * Nc, 256, 0, stream>>>(coords, smask, Wd1, bd1, Wd2, bd2, biasb);
    attn_kernel<<<Bc * Hc * (Nc / 4), 256, 0, stream>>>(Yq, Yk, Yv, biasb, attn);
    oproj_kernel<<<dim3(16, 8), 256, 0, stream>>>(attn, Wo, bo, yout);
    bcast_kernel<<<Bc * Nc, 256, 0, stream>>>(yout, out);
}

// Round 2
// 602.433 us; speedup vs baseline: 1.2902x; 1.2902x over previous
//
#include <hip/hip_runtime.h>
#include <math.h>

#define Bc 4
#define Nc 256
#define Tc 128
#define Dc 512
#define Hc 8
#define HDc 64

__device__ __forceinline__ float4 f4add(float4 a, float4 b) {
    return make_float4(a.x + b.x, a.y + b.y, a.z + b.z, a.w + b.w);
}

// swizzled float4-unit index for 64x64 float tile stored as 1024 float4s
// row 0..63, k4 0..15;  (row>>2) spreads banks across the 4-col fragment reads
#define SWZ(row, k4) (((row) << 4) | ((k4) ^ (((row) >> 2) & 15)))

// ---------------- Kernel 1: x_repr = mean over T -------------------------
// grid: B*N blocks, 256 threads; split T in halves, LDS combine.
__global__ __launch_bounds__(256) void mean_kernel(const float* __restrict__ x,
                                                   float* __restrict__ xr) {
    const int bn = blockIdx.x;
    const int col = threadIdx.x & 127;   // float4 column
    const int half = threadIdx.x >> 7;   // 0/1
    const float4* xp = (const float4*)x + (size_t)bn * (Tc * Dc / 4)
                       + (size_t)(half * 64) * (Dc / 4) + col;
    float4 a0 = make_float4(0.f, 0.f, 0.f, 0.f), a1 = a0, a2 = a0, a3 = a0;
    for (int t = 0; t < 64; t += 4) {
        a0 = f4add(a0, xp[(size_t)(t + 0) * (Dc / 4)]);
        a1 = f4add(a1, xp[(size_t)(t + 1) * (Dc / 4)]);
        a2 = f4add(a2, xp[(size_t)(t + 2) * (Dc / 4)]);
        a3 = f4add(a3, xp[(size_t)(t + 3) * (Dc / 4)]);
    }
    __shared__ float4 red[256];
    red[threadIdx.x] = f4add(f4add(a0, a1), f4add(a2, a3));
    __syncthreads();
    if (threadIdx.x < 128) {
        float4 s = f4add(red[threadIdx.x], red[threadIdx.x + 128]);
        const float r = 1.0f / Tc;
        ((float4*)xr)[(size_t)bn * (Dc / 4) + threadIdx.x] =
            make_float4(s.x * r, s.y * r, s.z * r, s.w * r);
    }
}

// ---------------- GEMM core: acc(64x64 tile) = A(64xK) @ W(64xK)^T -------
// block = 256 threads, 4x4 per thread. Natural row-major float4 LDS tiles
// with XOR swizzle: b128 staging writes AND b128 fragment reads, no conflicts.
__device__ __forceinline__ void gemm_core(const float* __restrict__ A,
                                          const float* __restrict__ W,
                                          int i0, int j0, float acc[4][4]) {
    __shared__ float4 As4[1024];
    __shared__ float4 Ws4[1024];
    const int tid = threadIdx.x;
    const int ty = tid >> 4, tx = tid & 15;
    for (int kb = 0; kb < 8; ++kb) {
        const int k0 = kb * 64;
#pragma unroll
        for (int p = 0; p < 4; ++p) {
            const int idx = p * 256 + tid;
            const int row = idx >> 4, k4 = idx & 15;
            As4[SWZ(row, k4)] = *(const float4*)&A[(size_t)(i0 + row) * Dc + k0 + k4 * 4];
            Ws4[SWZ(row, k4)] = *(const float4*)&W[(size_t)(j0 + row) * Dc + k0 + k4 * 4];
        }
        __syncthreads();
#pragma unroll
        for (int kk4 = 0; kk4 < 16; ++kk4) {
            float4 a[4], w[4];
#pragma unroll
            for (int q = 0; q < 4; ++q) a[q] = As4[SWZ(ty * 4 + q, kk4)];
#pragma unroll
            for (int c = 0; c < 4; ++c) w[c] = Ws4[SWZ(tx * 4 + c, kk4)];
#pragma unroll
            for (int q = 0; q < 4; ++q)
#pragma unroll
                for (int c = 0; c < 4; ++c) {
                    acc[q][c] += a[q].x * w[c].x;
                    acc[q][c] += a[q].y * w[c].y;
                    acc[q][c] += a[q].z * w[c].z;
                    acc[q][c] += a[q].w * w[c].w;
                }
        }
        __syncthreads();
    }
}

// Fused QKV: grid (16, 24); blockIdx.y>>3 selects matrix, &7 selects j-tile.
// K is stored TRANSPOSED: Kt[((b*8+h)*64 + hd)*256 + n]  (n contiguous)
__global__ __launch_bounds__(256) void qkv_kernel(
    const float* __restrict__ xr, const float* __restrict__ Wq, const float* __restrict__ bq,
    const float* __restrict__ Wk, const float* __restrict__ bk,
    const float* __restrict__ Wv, const float* __restrict__ bv,
    float* __restrict__ Yq, float* __restrict__ Kt, float* __restrict__ Yv) {
    const int it = blockIdx.x;
    const int mat = blockIdx.y >> 3;
    const int jt = blockIdx.y & 7;
    const float* W = (mat == 0) ? Wq : (mat == 1) ? Wk : Wv;
    const float* bias = (mat == 0) ? bq : (mat == 1) ? bk : bv;
    const int i0 = it * 64, j0 = jt * 64;
    float acc[4][4] = {{0.f}};
    gemm_core(xr, W, i0, j0, acc);
    const int ty = threadIdx.x >> 4, tx = threadIdx.x & 15;
    if (mat == 1) {
        // transposed store for K
        const int b = i0 >> 8;
        const int n0 = (i0 & 255) + ty * 4;
#pragma unroll
        for (int c = 0; c < 4; ++c) {
            const int j = j0 + tx * 4 + c;
            const float bj = bias[j];
            float4 v = make_float4(acc[0][c] + bj, acc[1][c] + bj,
                                   acc[2][c] + bj, acc[3][c] + bj);
            *(float4*)&Kt[(((size_t)b * Hc + jt) * HDc + (tx * 4 + c)) * Nc + n0] = v;
        }
    } else {
        float* Y = (mat == 0) ? Yq : Yv;
#pragma unroll
        for (int r = 0; r < 4; ++r) {
            const int i = i0 + ty * 4 + r;
            const int j = j0 + tx * 4;
            float4 o = make_float4(acc[r][0] + bias[j + 0], acc[r][1] + bias[j + 1],
                                   acc[r][2] + bias[j + 2], acc[r][3] + bias[j + 3]);
            *(float4*)&Y[(size_t)i * Dc + j] = o;
        }
    }
}

// O projection: grid (16, 8)
__global__ __launch_bounds__(256) void oproj_kernel(const float* __restrict__ attn,
                                                    const float* __restrict__ Wo,
                                                    const float* __restrict__ bo,
                                                    float* __restrict__ Y) {
    const int i0 = blockIdx.x * 64, j0 = blockIdx.y * 64;
    float acc[4][4] = {{0.f}};
    gemm_core(attn, Wo, i0, j0, acc);
    const int ty = threadIdx.x >> 4, tx = threadIdx.x & 15;
#pragma unroll
    for (int r = 0; r < 4; ++r) {
        const int i = i0 + ty * 4 + r;
        const int j = j0 + tx * 4;
        float4 o = make_float4(acc[r][0] + bo[j + 0], acc[r][1] + bo[j + 1],
                               acc[r][2] + bo[j + 2], acc[r][3] + bo[j + 3]);
        *(float4*)&Y[(size_t)i * Dc + j] = o;
    }
}

// ---------------- Kernel 3: bias[b,h,n,m] (haversine MLP + mask) ---------
__global__ __launch_bounds__(256) void bias_kernel(
    const float* __restrict__ coords, const int* __restrict__ mask,
    const float* __restrict__ Wd1, const float* __restrict__ bd1,
    const float* __restrict__ Wd2, const float* __restrict__ bd2,
    float* __restrict__ biasb) {
    const int b = blockIdx.x >> 8;
    const int n = blockIdx.x & 255;
    const int m = threadIdx.x;
    __shared__ float swd1[64], sbd1[64], swd2[512], sbd2[8];
    if (threadIdx.x < 64) {
        swd1[threadIdx.x] = Wd1[threadIdx.x];
        sbd1[threadIdx.x] = bd1[threadIdx.x];
    }
    if (threadIdx.x < 8) sbd2[threadIdx.x] = bd2[threadIdx.x];
    swd2[threadIdx.x] = Wd2[threadIdx.x];
    swd2[threadIdx.x + 256] = Wd2[threadIdx.x + 256];
    __syncthreads();

    const float DEG = 0.017453292519943295f;  // pi/180
    float lat1 = coords[((size_t)b * Nc + n) * 2 + 0] * DEG;
    float lon1 = coords[((size_t)b * Nc + n) * 2 + 1] * DEG;
    float lat2 = coords[((size_t)b * Nc + m) * 2 + 0] * DEG;
    float lon2 = coords[((size_t)b * Nc + m) * 2 + 1] * DEG;
    float sdlat = sinf((lat2 - lat1) * 0.5f);
    float sdlon = sinf((lon2 - lon1) * 0.5f);
    float a = sdlat * sdlat + cosf(lat1) * cosf(lat2) * sdlon * sdlon;
    a = fminf(fmaxf(a, 0.0f), 1.0f);
    float c = 2.0f * atan2f(sqrtf(a), sqrtf(1.0f - a));
    float dist = 6371.0f * c;

    float acc[8];
#pragma unroll
    for (int h = 0; h < 8; ++h) acc[h] = sbd2[h];
#pragma unroll 8
    for (int k = 0; k < 64; ++k) {
        float hm = fmaxf(dist * swd1[k] + sbd1[k], 0.0f);
#pragma unroll
        for (int h = 0; h < 8; ++h) acc[h] += hm * swd2[h * 64 + k];
    }
    const bool masked = (mask[(size_t)b * Nc + m] == 0);
#pragma unroll
    for (int h = 0; h < 8; ++h) {
        biasb[(((size_t)(b * Hc + h) * Nc + n) * Nc) + m] = masked ? -1e30f : acc[h];
    }
}

// ---------------- Kernel 4: attention --------------------------------------
// grid: B*H*(N/4) = 2048 blocks, 256 threads = 4 waves; wave = one query row.
// Scores: lane handles 4 m's via float4 over transposed K (coalesced 1KB/instr).
__global__ __launch_bounds__(256) void attn_kernel(
    const float* __restrict__ Yq, const float* __restrict__ Kt,
    const float* __restrict__ Yv, const float* __restrict__ biasb,
    float* __restrict__ attnO) {
    const int bh = blockIdx.x >> 6;   // 0..31
    const int ng = blockIdx.x & 63;   // 0..63
    const int b = bh >> 3, h = bh & 7;
    const int wave = threadIdx.x >> 6;
    const int lane = threadIdx.x & 63;
    const int n = ng * 4 + wave;

    __shared__ float sq[4][64];
    __shared__ float sw[4][256];

    // stage q row (fold 1/sqrt(hd)=1/8 into q)
    sq[wave][lane] = Yq[((size_t)(b * Nc + n)) * Dc + h * HDc + lane] * 0.125f;
    __syncthreads();

    // scores for m = lane*4 .. lane*4+3
    const float4* ktp = (const float4*)(Kt + (size_t)bh * HDc * Nc);
    float4 acc = make_float4(0.f, 0.f, 0.f, 0.f);
#pragma unroll 16
    for (int k = 0; k < 64; ++k) {
        const float qk = sq[wave][k];
        const float4 kv = ktp[k * 64 + lane];
        acc.x += qk * kv.x; acc.y += qk * kv.y;
        acc.z += qk * kv.z; acc.w += qk * kv.w;
    }
    const float4 bi = ((const float4*)(biasb + ((size_t)bh * Nc + n) * Nc))[lane];
    float4 s = make_float4(acc.x + bi.x, acc.y + bi.y, acc.z + bi.z, acc.w + bi.w);
    float mx = fmaxf(fmaxf(s.x, s.y), fmaxf(s.z, s.w));
#pragma unroll
    for (int off = 32; off > 0; off >>= 1) mx = fmaxf(mx, __shfl_xor(mx, off, 64));

    float4 e = make_float4(expf(s.x - mx), expf(s.y - mx), expf(s.z - mx), expf(s.w - mx));
    ((float4*)sw[wave])[lane] = e;
    float sum = e.x + e.y + e.z + e.w;
#pragma unroll
    for (int off = 32; off > 0; off >>= 1) sum += __shfl_xor(sum, off, 64);
    const float inv = 1.0f / sum;
    __syncthreads();

    // out[n, d=lane] = sum_m w_m * V[m][d]   (V reads: 256B coalesced per m)
    float o = 0.f;
    const float* vb = Yv + (size_t)b * Nc * Dc + h * HDc + lane;
    const float4* sw4 = (const float4*)sw[wave];
#pragma unroll 8
    for (int mq = 0; mq < 64; ++mq) {
        float4 w4 = sw4[mq];
        const int m = mq * 4;
        o += w4.x * vb[(size_t)(m + 0) * Dc];
        o += w4.y * vb[(size_t)(m + 1) * Dc];
        o += w4.z * vb[(size_t)(m + 2) * Dc];
        o += w4.w * vb[(size_t)(m + 3) * Dc];
    }
    attnO[((size_t)(b * Nc + n)) * Dc + h * HDc + lane] = o * inv;
}

// ---------------- Kernel 6: broadcast over T -------------------------------
// grid: 2*B*N blocks, 256 threads (each block writes 64 t-slots = 128 KB)
__global__ __launch_bounds__(256) void bcast_kernel(const float* __restrict__ y,
                                                    float* __restrict__ out) {
    const int bn = blockIdx.x >> 1;
    const int half = blockIdx.x & 1;
    __shared__ float4 row[128];
    if (threadIdx.x < 128) row[threadIdx.x] = ((const float4*)y)[(size_t)bn * 128 + threadIdx.x];
    __syncthreads();
    float4* op = (float4*)out + (size_t)bn * (Tc * Dc / 4) + (size_t)half * 8192;
#pragma unroll 4
    for (int it = 0; it < 32; ++it) {
        const int idx = it * 256 + threadIdx.x;
        op[idx] = row[idx & 127];
    }
}

extern "C" void kernel_launch(void* const* d_in, const int* in_sizes, int n_in,
                              void* d_out, int out_size, void* d_ws, size_t ws_size,
                              hipStream_t stream) {
    const float* x      = (const float*)d_in[0];
    const float* coords = (const float*)d_in[1];
    const int*   smask  = (const int*)d_in[2];
    const float* Wq = (const float*)d_in[3];  const float* bq = (const float*)d_in[4];
    const float* Wk = (const float*)d_in[5];  const float* bk = (const float*)d_in[6];
    const float* Wv = (const float*)d_in[7];  const float* bv = (const float*)d_in[8];
    const float* Wo = (const float*)d_in[9];  const float* bo = (const float*)d_in[10];
    const float* Wd1 = (const float*)d_in[11]; const float* bd1 = (const float*)d_in[12];
    const float* Wd2 = (const float*)d_in[13]; const float* bd2 = (const float*)d_in[14];
    float* out = (float*)d_out;

    float* ws    = (float*)d_ws;
    const size_t BND = (size_t)Bc * Nc * Dc;           // 524288
    float* xr    = ws;
    float* Yq    = xr + BND;
    float* Kt    = Yq + BND;                            // transposed K
    float* Yv    = Kt + BND;
    float* biasb = Yv + BND;                            // B*H*N*N = 2097152
    float* attn  = biasb + (size_t)Bc * Hc * Nc * Nc;
    float* yout  = attn + BND;

    mean_kernel<<<Bc * Nc, 256, 0, stream>>>(x, xr);
    qkv_kernel<<<dim3(16, 24), 256, 0, stream>>>(xr, Wq, bq, Wk, bk, Wv, bv, Yq, Kt, Yv);
    bias_kernel<<<Bc * Nc, 256, 0, stream>>>(coords, smask, Wd1, bd1, Wd2, bd2, biasb);
    attn_kernel<<<Bc * Hc * (Nc / 4), 256, 0, stream>>>(Yq, Kt, Yv, biasb, attn);
    oproj_kernel<<<dim3(16, 8), 256, 0, stream>>>(attn, Wo, bo, yout);
    bcast_kernel<<<2 * Bc * Nc, 256, 0, stream>>>(yout, out);
}

// Round 3
// 594.525 us; speedup vs baseline: 1.3073x; 1.0133x over previous
//
#include <hip/hip_runtime.h>
#include <math.h>

#define Bc 4
#define Nc 256
#define Tc 128
#define Dc 512
#define Hc 8
#define HDc 64

typedef float f4v __attribute__((ext_vector_type(4)));

// swizzled float4-unit index for 64x64 float tile stored as 1024 float4s
#define SWZ(row, k4) (((row) << 4) | ((k4) ^ (((row) >> 2) & 15)))

// ---------------- Kernel 1: x_repr = mean over T -------------------------
// grid: B*N blocks, 256 threads; half-T split, 8 independent accumulators,
// nontemporal loads (x streamed once — don't thrash L2).
__global__ __launch_bounds__(256) void mean_kernel(const float* __restrict__ x,
                                                   float* __restrict__ xr) {
    const int bn = blockIdx.x;
    const int col = threadIdx.x & 127;
    const int half = threadIdx.x >> 7;
    const f4v* xp = (const f4v*)x + (size_t)bn * (Tc * Dc / 4)
                    + (size_t)(half * 64) * (Dc / 4) + col;
    f4v a[8];
#pragma unroll
    for (int u = 0; u < 8; ++u) a[u] = (f4v)(0.f);
    for (int t = 0; t < 64; t += 8) {
#pragma unroll
        for (int u = 0; u < 8; ++u)
            a[u] += __builtin_nontemporal_load(xp + (size_t)(t + u) * (Dc / 4));
    }
    f4v s = ((a[0] + a[1]) + (a[2] + a[3])) + ((a[4] + a[5]) + (a[6] + a[7]));
    __shared__ f4v red[256];
    red[threadIdx.x] = s;
    __syncthreads();
    if (threadIdx.x < 128) {
        f4v r = (red[threadIdx.x] + red[threadIdx.x + 128]) * (1.0f / Tc);
        ((f4v*)xr)[(size_t)bn * (Dc / 4) + threadIdx.x] = r;
    }
}

// ---------------- GEMM core with register-prefetch pipeline --------------
// acc(64x64 tile) = A(64xK) @ W(64xK)^T ; 256 threads, 4x4 per thread.
__device__ __forceinline__ void gemm_core(const float* __restrict__ A,
                                          const float* __restrict__ W,
                                          int i0, int j0, float acc[4][4]) {
    __shared__ float4 As4[1024];
    __shared__ float4 Ws4[1024];
    const int tid = threadIdx.x;
    const int ty = tid >> 4, tx = tid & 15;
    float4 pa[4], pw[4];
#pragma unroll
    for (int p = 0; p < 4; ++p) {
        pa[p] = *(const float4*)&A[(size_t)(i0 + p * 16 + ty) * Dc + tx * 4];
        pw[p] = *(const float4*)&W[(size_t)(j0 + p * 16 + ty) * Dc + tx * 4];
    }
    for (int kb = 0; kb < 8; ++kb) {
#pragma unroll
        for (int p = 0; p < 4; ++p) {
            As4[SWZ(p * 16 + ty, tx)] = pa[p];
            Ws4[SWZ(p * 16 + ty, tx)] = pw[p];
        }
        __syncthreads();
        if (kb < 7) {
            const int k0 = (kb + 1) * 64;
#pragma unroll
            for (int p = 0; p < 4; ++p) {
                pa[p] = *(const float4*)&A[(size_t)(i0 + p * 16 + ty) * Dc + k0 + tx * 4];
                pw[p] = *(const float4*)&W[(size_t)(j0 + p * 16 + ty) * Dc + k0 + tx * 4];
            }
        }
#pragma unroll
        for (int kk4 = 0; kk4 < 16; ++kk4) {
            float4 a[4], w[4];
#pragma unroll
            for (int q = 0; q < 4; ++q) a[q] = As4[SWZ(ty * 4 + q, kk4)];
#pragma unroll
            for (int c = 0; c < 4; ++c) w[c] = Ws4[SWZ(tx * 4 + c, kk4)];
#pragma unroll
            for (int q = 0; q < 4; ++q)
#pragma unroll
                for (int c = 0; c < 4; ++c) {
                    acc[q][c] += a[q].x * w[c].x;
                    acc[q][c] += a[q].y * w[c].y;
                    acc[q][c] += a[q].z * w[c].z;
                    acc[q][c] += a[q].w * w[c].w;
                }
        }
        __syncthreads();
    }
}

// Fused QKV: grid (16, 24). K stored TRANSPOSED: Kt[((b*8+h)*64+hd)*256+n]
__global__ __launch_bounds__(256) void qkv_kernel(
    const float* __restrict__ xr, const float* __restrict__ Wq, const float* __restrict__ bq,
    const float* __restrict__ Wk, const float* __restrict__ bk,
    const float* __restrict__ Wv, const float* __restrict__ bv,
    float* __restrict__ Yq, float* __restrict__ Kt, float* __restrict__ Yv) {
    const int it = blockIdx.x;
    const int mat = blockIdx.y >> 3;
    const int jt = blockIdx.y & 7;
    const float* W = (mat == 0) ? Wq : (mat == 1) ? Wk : Wv;
    const float* bias = (mat == 0) ? bq : (mat == 1) ? bk : bv;
    const int i0 = it * 64, j0 = jt * 64;
    float acc[4][4] = {{0.f}};
    gemm_core(xr, W, i0, j0, acc);
    const int ty = threadIdx.x >> 4, tx = threadIdx.x & 15;
    if (mat == 1) {
        const int b = i0 >> 8;
        const int n0 = (i0 & 255) + ty * 4;
#pragma unroll
        for (int c = 0; c < 4; ++c) {
            const int j = j0 + tx * 4 + c;
            const float bj = bias[j];
            float4 v = make_float4(acc[0][c] + bj, acc[1][c] + bj,
                                   acc[2][c] + bj, acc[3][c] + bj);
            *(float4*)&Kt[(((size_t)b * Hc + jt) * HDc + (tx * 4 + c)) * Nc + n0] = v;
        }
    } else {
        float* Y = (mat == 0) ? Yq : Yv;
#pragma unroll
        for (int r = 0; r < 4; ++r) {
            const int i = i0 + ty * 4 + r;
            const int j = j0 + tx * 4;
            float4 o = make_float4(acc[r][0] + bias[j + 0], acc[r][1] + bias[j + 1],
                                   acc[r][2] + bias[j + 2], acc[r][3] + bias[j + 3]);
            *(float4*)&Y[(size_t)i * Dc + j] = o;
        }
    }
}

// ---------------- Kernel 3: attention with fused haversine-MLP bias ------
// grid: B*H*(N/4) = 2048 blocks, 256 threads; wave = one query row.
__global__ __launch_bounds__(256) void attn_kernel(
    const float* __restrict__ Yq, const float* __restrict__ Kt,
    const float* __restrict__ Yv, const float* __restrict__ coords,
    const int* __restrict__ mask, const float* __restrict__ Wd1,
    const float* __restrict__ bd1, const float* __restrict__ Wd2,
    const float* __restrict__ bd2, float* __restrict__ attnO) {
    const int bh = blockIdx.x >> 6;
    const int ng = blockIdx.x & 63;
    const int b = bh >> 3, h = bh & 7;
    const int tid = threadIdx.x;
    const int wave = tid >> 6, lane = tid & 63;
    const int n = ng * 4 + wave;

    __shared__ float sq[4][64];
    __shared__ float sw[4][256];
    __shared__ float slat[256], slon[256], scl[256];
    __shared__ float swd1[64], sbd1[64], swd2[64];
    __shared__ int smk[256];

    {
        const float DEG = 0.017453292519943295f;
        float la = coords[((size_t)b * Nc + tid) * 2 + 0] * DEG;
        float lo = coords[((size_t)b * Nc + tid) * 2 + 1] * DEG;
        slat[tid] = la; slon[tid] = lo; scl[tid] = cosf(la);
        smk[tid] = mask[(size_t)b * Nc + tid];
        if (tid < 64) {
            swd1[tid] = Wd1[tid];
            sbd1[tid] = bd1[tid];
            swd2[tid] = Wd2[h * 64 + tid];
        }
    }
    sq[wave][lane] = Yq[((size_t)(b * Nc + n)) * Dc + h * HDc + lane] * 0.125f;
    __syncthreads();

    // scores for m = lane*4 .. lane*4+3 (coalesced 1KB/instr over Kt)
    const float4* ktp = (const float4*)(Kt + (size_t)bh * HDc * Nc);
    float4 acc = make_float4(0.f, 0.f, 0.f, 0.f);
#pragma unroll 16
    for (int k = 0; k < 64; ++k) {
        const float qk = sq[wave][k];
        const float4 kv = ktp[k * 64 + lane];
        acc.x += qk * kv.x; acc.y += qk * kv.y;
        acc.z += qk * kv.z; acc.w += qk * kv.w;
    }

    // haversine distance + 2-layer MLP bias, computed in-register
    const float lat1 = slat[n], lon1 = slon[n], cl1 = scl[n];
    float dist[4];
#pragma unroll
    for (int j = 0; j < 4; ++j) {
        const int m = lane * 4 + j;
        float sdlat = sinf((slat[m] - lat1) * 0.5f);
        float sdlon = sinf((slon[m] - lon1) * 0.5f);
        float a = sdlat * sdlat + cl1 * scl[m] * sdlon * sdlon;
        a = fminf(fmaxf(a, 0.f), 1.f);
        dist[j] = 12742.0f * atan2f(sqrtf(a), sqrtf(1.0f - a));  // 2*6371
    }
    const float b2 = bd2[h];
    float bias[4] = {b2, b2, b2, b2};
#pragma unroll 4
    for (int k = 0; k < 64; ++k) {
        const float w1 = swd1[k], c1 = sbd1[k], w2 = swd2[k];
#pragma unroll
        for (int j = 0; j < 4; ++j)
            bias[j] += fmaxf(dist[j] * w1 + c1, 0.f) * w2;
    }
    float s[4] = {acc.x + bias[0], acc.y + bias[1], acc.z + bias[2], acc.w + bias[3]};
#pragma unroll
    for (int j = 0; j < 4; ++j)
        if (smk[lane * 4 + j] == 0) s[j] = -1e30f;

    float mx = fmaxf(fmaxf(s[0], s[1]), fmaxf(s[2], s[3]));
#pragma unroll
    for (int off = 32; off > 0; off >>= 1) mx = fmaxf(mx, __shfl_xor(mx, off, 64));
    float e0 = expf(s[0] - mx), e1 = expf(s[1] - mx);
    float e2 = expf(s[2] - mx), e3 = expf(s[3] - mx);
    ((float4*)sw[wave])[lane] = make_float4(e0, e1, e2, e3);
    float sum = e0 + e1 + e2 + e3;
#pragma unroll
    for (int off = 32; off > 0; off >>= 1) sum += __shfl_xor(sum, off, 64);
    const float inv = 1.0f / sum;
    __syncthreads();

    // PV: lane -> (mo, d4); each load instr = 4 x 256B segments (1KB/instr)
    const int mo = lane >> 4, d4 = lane & 15;
    const float* vbase = Yv + (size_t)b * Nc * Dc + h * HDc + d4 * 4;
    const float* wv = sw[wave];
    float4 o = make_float4(0.f, 0.f, 0.f, 0.f);
#pragma unroll 8
    for (int mq = 0; mq < 64; ++mq) {
        const int m = mq * 4 + mo;
        const float wm = wv[m];
        const float4 v = *(const float4*)&vbase[(size_t)m * Dc];
        o.x += wm * v.x; o.y += wm * v.y; o.z += wm * v.z; o.w += wm * v.w;
    }
#pragma unroll
    for (int off = 16; off <= 32; off <<= 1) {
        o.x += __shfl_xor(o.x, off, 64);
        o.y += __shfl_xor(o.y, off, 64);
        o.z += __shfl_xor(o.z, off, 64);
        o.w += __shfl_xor(o.w, off, 64);
    }
    if (mo == 0) {
        float4 r = make_float4(o.x * inv, o.y * inv, o.z * inv, o.w * inv);
        *(float4*)&attnO[((size_t)(b * Nc + n)) * Dc + h * HDc + d4 * 4] = r;
    }
}

// ---------------- Kernel 4: O-projection fused with T-broadcast ----------
// grid (16, 8, 2): z splits the t-range (GEMM duplicated, writes spread).
__global__ __launch_bounds__(256) void oproj_bcast_kernel(
    const float* __restrict__ attnI, const float* __restrict__ Wo,
    const float* __restrict__ bo, float* __restrict__ out) {
    const int i0 = blockIdx.x * 64, j0 = blockIdx.y * 64;
    const int z = blockIdx.z;
    float acc[4][4] = {{0.f}};
    gemm_core(attnI, Wo, i0, j0, acc);

    __shared__ f4v tile[1024];  // 64 rows x 16 float4
    const int ty = threadIdx.x >> 4, tx = threadIdx.x & 15;
#pragma unroll
    for (int q = 0; q < 4; ++q) {
        const int j = j0 + tx * 4;
        f4v v;
        v.x = acc[q][0] + bo[j + 0]; v.y = acc[q][1] + bo[j + 1];
        v.z = acc[q][2] + bo[j + 2]; v.w = acc[q][3] + bo[j + 3];
        tile[(ty * 4 + q) * 16 + tx] = v;
    }
    __syncthreads();

    const int d4 = threadIdx.x & 15;   // float4 within 64-col tile
    const int sub = threadIdx.x >> 4;  // 0..15 t-offset group
    for (int r = 0; r < 64; ++r) {
        const f4v val = tile[r * 16 + d4];
        float* rowbase = out + (size_t)(i0 + r) * Tc * Dc + j0;
#pragma unroll
        for (int tt = 0; tt < 4; ++tt) {
            const int t = z * 64 + tt * 16 + sub;
            __builtin_nontemporal_store(val, (f4v*)(rowbase + (size_t)t * Dc) + d4);
        }
    }
}

extern "C" void kernel_launch(void* const* d_in, const int* in_sizes, int n_in,
                              void* d_out, int out_size, void* d_ws, size_t ws_size,
                              hipStream_t stream) {
    const float* x      = (const float*)d_in[0];
    const float* coords = (const float*)d_in[1];
    const int*   smask  = (const int*)d_in[2];
    const float* Wq = (const float*)d_in[3];  const float* bq = (const float*)d_in[4];
    const float* Wk = (const float*)d_in[5];  const float* bk = (const float*)d_in[6];
    const float* Wv = (const float*)d_in[7];  const float* bv = (const float*)d_in[8];
    const float* Wo = (const float*)d_in[9];  const float* bo = (const float*)d_in[10];
    const float* Wd1 = (const float*)d_in[11]; const float* bd1 = (const float*)d_in[12];
    const float* Wd2 = (const float*)d_in[13]; const float* bd2 = (const float*)d_in[14];
    float* out = (float*)d_out;

    float* ws    = (float*)d_ws;
    const size_t BND = (size_t)Bc * Nc * Dc;  // 524288
    float* xr    = ws;
    float* Yq    = xr + BND;
    float* Kt    = Yq + BND;   // transposed K
    float* Yv    = Kt + BND;
    float* attn  = Yv + BND;

    mean_kernel<<<Bc * Nc, 256, 0, stream>>>(x, xr);
    qkv_kernel<<<dim3(16, 24), 256, 0, stream>>>(xr, Wq, bq, Wk, bk, Wv, bv, Yq, Kt, Yv);
    attn_kernel<<<Bc * Hc * (Nc / 4), 256, 0, stream>>>(Yq, Kt, Yv, coords, smask,
                                                        Wd1, bd1, Wd2, bd2, attn);
    oproj_bcast_kernel<<<dim3(16, 8, 2), 256, 0, stream>>>(attn, Wo, bo, out);
}

// Round 4
// 587.398 us; speedup vs baseline: 1.3232x; 1.0121x over previous
//
#include <hip/hip_runtime.h>
#include <math.h>

#define Bc 4
#define Nc 256
#define Tc 128
#define Dc 512
#define Hc 8
#define HDc 64

typedef float f4v __attribute__((ext_vector_type(4)));

// swizzled float4-unit index for 64x64 float tile stored as 1024 float4s
#define SWZ(row, k4) (((row) << 4) | ((k4) ^ (((row) >> 2) & 15)))

// ---------------- Kernel 1: x_repr = mean over T -------------------------
__global__ __launch_bounds__(256) void mean_kernel(const float* __restrict__ x,
                                                   float* __restrict__ xr) {
    const int bn = blockIdx.x;
    const int col = threadIdx.x & 127;
    const int half = threadIdx.x >> 7;
    const f4v* xp = (const f4v*)x + (size_t)bn * (Tc * Dc / 4)
                    + (size_t)(half * 64) * (Dc / 4) + col;
    f4v a[8];
#pragma unroll
    for (int u = 0; u < 8; ++u) a[u] = (f4v)(0.f);
    for (int t = 0; t < 64; t += 8) {
#pragma unroll
        for (int u = 0; u < 8; ++u)
            a[u] += __builtin_nontemporal_load(xp + (size_t)(t + u) * (Dc / 4));
    }
    f4v s = ((a[0] + a[1]) + (a[2] + a[3])) + ((a[4] + a[5]) + (a[6] + a[7]));
    __shared__ f4v red[256];
    red[threadIdx.x] = s;
    __syncthreads();
    if (threadIdx.x < 128) {
        f4v r = (red[threadIdx.x] + red[threadIdx.x + 128]) * (1.0f / Tc);
        ((f4v*)xr)[(size_t)bn * (Dc / 4) + threadIdx.x] = r;
    }
}

// ---------------- GEMM core with register-prefetch pipeline --------------
__device__ __forceinline__ void gemm_core(const float* __restrict__ A,
                                          const float* __restrict__ W,
                                          int i0, int j0, float acc[4][4]) {
    __shared__ float4 As4[1024];
    __shared__ float4 Ws4[1024];
    const int tid = threadIdx.x;
    const int ty = tid >> 4, tx = tid & 15;
    float4 pa[4], pw[4];
#pragma unroll
    for (int p = 0; p < 4; ++p) {
        pa[p] = *(const float4*)&A[(size_t)(i0 + p * 16 + ty) * Dc + tx * 4];
        pw[p] = *(const float4*)&W[(size_t)(j0 + p * 16 + ty) * Dc + tx * 4];
    }
    for (int kb = 0; kb < 8; ++kb) {
#pragma unroll
        for (int p = 0; p < 4; ++p) {
            As4[SWZ(p * 16 + ty, tx)] = pa[p];
            Ws4[SWZ(p * 16 + ty, tx)] = pw[p];
        }
        __syncthreads();
        if (kb < 7) {
            const int k0 = (kb + 1) * 64;
#pragma unroll
            for (int p = 0; p < 4; ++p) {
                pa[p] = *(const float4*)&A[(size_t)(i0 + p * 16 + ty) * Dc + k0 + tx * 4];
                pw[p] = *(const float4*)&W[(size_t)(j0 + p * 16 + ty) * Dc + k0 + tx * 4];
            }
        }
#pragma unroll
        for (int kk4 = 0; kk4 < 16; ++kk4) {
            float4 a[4], w[4];
#pragma unroll
            for (int q = 0; q < 4; ++q) a[q] = As4[SWZ(ty * 4 + q, kk4)];
#pragma unroll
            for (int c = 0; c < 4; ++c) w[c] = Ws4[SWZ(tx * 4 + c, kk4)];
#pragma unroll
            for (int q = 0; q < 4; ++q)
#pragma unroll
                for (int c = 0; c < 4; ++c) {
                    acc[q][c] += a[q].x * w[c].x;
                    acc[q][c] += a[q].y * w[c].y;
                    acc[q][c] += a[q].z * w[c].z;
                    acc[q][c] += a[q].w * w[c].w;
                }
        }
        __syncthreads();
    }
}

// Fused QKV: grid (16, 24). K stored TRANSPOSED: Kt[((b*8+h)*64+hd)*256+n]
__global__ __launch_bounds__(256) void qkv_kernel(
    const float* __restrict__ xr, const float* __restrict__ Wq, const float* __restrict__ bq,
    const float* __restrict__ Wk, const float* __restrict__ bk,
    const float* __restrict__ Wv, const float* __restrict__ bv,
    float* __restrict__ Yq, float* __restrict__ Kt, float* __restrict__ Yv) {
    const int it = blockIdx.x;
    const int mat = blockIdx.y >> 3;
    const int jt = blockIdx.y & 7;
    const float* W = (mat == 0) ? Wq : (mat == 1) ? Wk : Wv;
    const float* bias = (mat == 0) ? bq : (mat == 1) ? bk : bv;
    const int i0 = it * 64, j0 = jt * 64;
    float acc[4][4] = {{0.f}};
    gemm_core(xr, W, i0, j0, acc);
    const int ty = threadIdx.x >> 4, tx = threadIdx.x & 15;
    if (mat == 1) {
        const int b = i0 >> 8;
        const int n0 = (i0 & 255) + ty * 4;
#pragma unroll
        for (int c = 0; c < 4; ++c) {
            const int j = j0 + tx * 4 + c;
            const float bj = bias[j];
            float4 v = make_float4(acc[0][c] + bj, acc[1][c] + bj,
                                   acc[2][c] + bj, acc[3][c] + bj);
            *(float4*)&Kt[(((size_t)b * Hc + jt) * HDc + (tx * 4 + c)) * Nc + n0] = v;
        }
    } else {
        float* Y = (mat == 0) ? Yq : Yv;
#pragma unroll
        for (int r = 0; r < 4; ++r) {
            const int i = i0 + ty * 4 + r;
            const int j = j0 + tx * 4;
            float4 o = make_float4(acc[r][0] + bias[j + 0], acc[r][1] + bias[j + 1],
                                   acc[r][2] + bias[j + 2], acc[r][3] + bias[j + 3]);
            *(float4*)&Y[(size_t)i * Dc + j] = o;
        }
    }
}

// ---------------- Kernel 3: attention, 4 queries per wave ----------------
// grid: 512 blocks = 32 bh x 16 query-groups; 256 threads = 4 waves.
// Each wave owns 4 query rows: every K/V load is reused 4x in registers.
__global__ __launch_bounds__(256) void attn_kernel(
    const float* __restrict__ Yq, const float* __restrict__ Kt,
    const float* __restrict__ Yv, const float* __restrict__ coords,
    const int* __restrict__ mask, const float* __restrict__ Wd1,
    const float* __restrict__ bd1, const float* __restrict__ Wd2,
    const float* __restrict__ bd2, float* __restrict__ attnO) {
    const int bh = blockIdx.x >> 4;        // 0..31
    const int g = blockIdx.x & 15;         // query group (16 rows)
    const int b = bh >> 3, h = bh & 7;
    const int tid = threadIdx.x;
    const int wid = tid >> 6, lane = tid & 63;
    const int n_base = g * 16;
    const int q0 = wid * 4;                // local query index of this wave

    __shared__ float sq[16][64];           // q rows, pre-scaled
    __shared__ float sw[16][256];          // softmax numerators
    __shared__ float slat[256], slon[256], scl[256];
    __shared__ float swd1[64], sbd1[64], swd2[64];
    __shared__ int smk[256];

    {
        const float DEG = 0.017453292519943295f;
        float la = coords[((size_t)b * Nc + tid) * 2 + 0] * DEG;
        float lo = coords[((size_t)b * Nc + tid) * 2 + 1] * DEG;
        slat[tid] = la; slon[tid] = lo; scl[tid] = __cosf(la);
        smk[tid] = mask[(size_t)b * Nc + tid];
        if (tid < 64) {
            swd1[tid] = Wd1[tid];
            sbd1[tid] = bd1[tid];
            swd2[tid] = Wd2[h * 64 + tid];
        }
#pragma unroll
        for (int r = 0; r < 4; ++r) {
            const int idx = r * 256 + tid;
            const int nl = idx >> 6, d = idx & 63;
            sq[nl][d] = Yq[((size_t)(b * Nc + n_base + nl)) * Dc + h * HDc + d] * 0.125f;
        }
    }
    __syncthreads();

    // ---- scores: lane owns m-strip lane*4..+3 for 4 queries ----
    const float4* ktp = (const float4*)(Kt + (size_t)bh * HDc * Nc);
    f4v acc[4];
#pragma unroll
    for (int j = 0; j < 4; ++j) acc[j] = (f4v)(0.f);
#pragma unroll 8
    for (int k = 0; k < 64; ++k) {
        const float4 kv = ktp[k * 64 + lane];
        const f4v kvv = {kv.x, kv.y, kv.z, kv.w};
#pragma unroll
        for (int j = 0; j < 4; ++j) acc[j] += sq[q0 + j][k] * kvv;
    }

    // ---- haversine + MLP bias, mask, softmax per query ----
    float inv[4];
    const int mbase = lane * 4;
    float mlat[4], mlon[4], mcl[4];
    int mk[4];
#pragma unroll
    for (int jm = 0; jm < 4; ++jm) {
        mlat[jm] = slat[mbase + jm]; mlon[jm] = slon[mbase + jm];
        mcl[jm] = scl[mbase + jm];   mk[jm] = smk[mbase + jm];
    }
#pragma unroll
    for (int j = 0; j < 4; ++j) {
        const int n = n_base + q0 + j;
        const float lat1 = slat[n], lon1 = slon[n], cl1 = scl[n];
        float s[4];
#pragma unroll
        for (int jm = 0; jm < 4; ++jm) {
            float sdlat = __sinf((mlat[jm] - lat1) * 0.5f);
            float sdlon = __sinf((mlon[jm] - lon1) * 0.5f);
            float a = sdlat * sdlat + cl1 * mcl[jm] * sdlon * sdlon;
            a = fminf(fmaxf(a, 0.f), 1.f);
            float dist = 12742.0f * atan2f(sqrtf(a), sqrtf(1.0f - a));
            float bias = 0.f;
#pragma unroll 8
            for (int k = 0; k < 64; ++k)
                bias += fmaxf(dist * swd1[k] + sbd1[k], 0.f) * swd2[k];
            s[jm] = acc[j][jm] + bias + bd2[h];
            if (mk[jm] == 0) s[jm] = -1e30f;
        }
        float mx = fmaxf(fmaxf(s[0], s[1]), fmaxf(s[2], s[3]));
#pragma unroll
        for (int off = 32; off > 0; off >>= 1) mx = fmaxf(mx, __shfl_xor(mx, off, 64));
        float e0 = __expf(s[0] - mx), e1 = __expf(s[1] - mx);
        float e2 = __expf(s[2] - mx), e3 = __expf(s[3] - mx);
        ((float4*)sw[q0 + j])[lane] = make_float4(e0, e1, e2, e3);
        float sum = e0 + e1 + e2 + e3;
#pragma unroll
        for (int off = 32; off > 0; off >>= 1) sum += __shfl_xor(sum, off, 64);
        inv[j] = 1.0f / sum;
    }
    __syncthreads();

    // ---- PV: lane -> (mo, d4); each V load reused for 4 queries ----
    const int mo = lane >> 4, d4 = lane & 15;
    const float* vbase = Yv + (size_t)b * Nc * Dc + h * HDc + d4 * 4;
    f4v o[4];
#pragma unroll
    for (int j = 0; j < 4; ++j) o[j] = (f4v)(0.f);
#pragma unroll 8
    for (int mq = 0; mq < 64; ++mq) {
        const int m = mq * 4 + mo;
        const f4v v = *(const f4v*)&vbase[(size_t)m * Dc];
#pragma unroll
        for (int j = 0; j < 4; ++j) o[j] += sw[q0 + j][m] * v;
    }
#pragma unroll
    for (int j = 0; j < 4; ++j) {
#pragma unroll
        for (int off = 16; off <= 32; off <<= 1) {
            o[j].x += __shfl_xor(o[j].x, off, 64);
            o[j].y += __shfl_xor(o[j].y, off, 64);
            o[j].z += __shfl_xor(o[j].z, off, 64);
            o[j].w += __shfl_xor(o[j].w, off, 64);
        }
        if (mo == 0) {
            const int n = n_base + q0 + j;
            f4v r = o[j] * inv[j];
            *(f4v*)&attnO[((size_t)(b * Nc + n)) * Dc + h * HDc + d4 * 4] = r;
        }
    }
}

// ---------------- Kernel 4: O-projection fused with T-broadcast ----------
__global__ __launch_bounds__(256) void oproj_bcast_kernel(
    const float* __restrict__ attnI, const float* __restrict__ Wo,
    const float* __restrict__ bo, float* __restrict__ out) {
    const int i0 = blockIdx.x * 64, j0 = blockIdx.y * 64;
    const int z = blockIdx.z;
    float acc[4][4] = {{0.f}};
    gemm_core(attnI, Wo, i0, j0, acc);

    __shared__ f4v tile[1024];  // 64 rows x 16 float4
    const int ty = threadIdx.x >> 4, tx = threadIdx.x & 15;
#pragma unroll
    for (int q = 0; q < 4; ++q) {
        const int j = j0 + tx * 4;
        f4v v;
        v.x = acc[q][0] + bo[j + 0]; v.y = acc[q][1] + bo[j + 1];
        v.z = acc[q][2] + bo[j + 2]; v.w = acc[q][3] + bo[j + 3];
        tile[(ty * 4 + q) * 16 + tx] = v;
    }
    __syncthreads();

    const int d4 = threadIdx.x & 15;
    const int sub = threadIdx.x >> 4;
    for (int r = 0; r < 64; ++r) {
        const f4v val = tile[r * 16 + d4];
        float* rowbase = out + (size_t)(i0 + r) * Tc * Dc + j0;
#pragma unroll
        for (int tt = 0; tt < 4; ++tt) {
            const int t = z * 64 + tt * 16 + sub;
            __builtin_nontemporal_store(val, (f4v*)(rowbase + (size_t)t * Dc) + d4);
        }
    }
}

extern "C" void kernel_launch(void* const* d_in, const int* in_sizes, int n_in,
                              void* d_out, int out_size, void* d_ws, size_t ws_size,
                              hipStream_t stream) {
    const float* x      = (const float*)d_in[0];
    const float* coords = (const float*)d_in[1];
    const int*   smask  = (const int*)d_in[2];
    const float* Wq = (const float*)d_in[3];  const float* bq = (const float*)d_in[4];
    const float* Wk = (const float*)d_in[5];  const float* bk = (const float*)d_in[6];
    const float* Wv = (const float*)d_in[7];  const float* bv = (const float*)d_in[8];
    const float* Wo = (const float*)d_in[9];  const float* bo = (const float*)d_in[10];
    const float* Wd1 = (const float*)d_in[11]; const float* bd1 = (const float*)d_in[12];
    const float* Wd2 = (const float*)d_in[13]; const float* bd2 = (const float*)d_in[14];
    float* out = (float*)d_out;

    float* ws    = (float*)d_ws;
    const size_t BND = (size_t)Bc * Nc * Dc;  // 524288
    float* xr    = ws;
    float* Yq    = xr + BND;
    float* Kt    = Yq + BND;   // transposed K
    float* Yv    = Kt + BND;
    float* attn  = Yv + BND;

    mean_kernel<<<Bc * Nc, 256, 0, stream>>>(x, xr);
    qkv_kernel<<<dim3(16, 24), 256, 0, stream>>>(xr, Wq, bq, Wk, bk, Wv, bv, Yq, Kt, Yv);
    attn_kernel<<<32 * 16, 256, 0, stream>>>(Yq, Kt, Yv, coords, smask,
                                             Wd1, bd1, Wd2, bd2, attn);
    oproj_bcast_kernel<<<dim3(16, 8, 2), 256, 0, stream>>>(attn, Wo, bo, out);
}